// Round 1
// 234.697 us; speedup vs baseline: 1.0768x; 1.0768x over previous
//
#include <hip/hip_runtime.h>

// ChineseCLIP vision attention, MI355X bf16-MFMA pipeline. Round 5:
//  - qkv_gemm rewritten as 256x256-tile, BK=64, 8-wave, 8-phase pipelined
//    GEMM (HK-style T2 swizzle + T3/T4 counted vmcnt + T5 setprio).
//    LDS 128KB double-buffered; global_load_lds with pre-swizzled source;
//    one vmcnt(4) per K-tile, never drained to 0 in the main loop.
//  - epilogue: two 256x128 half-passes through LDS (stride 136), same
//    verified frag-major Q/K/V layouts as before (attn kernel unchanged).
// B=32, T=257, D=1024, H=16, HD=64.

#define B_   32
#define T_   257
#define TP   272
#define H_   16
#define HD_  64
#define D_   1024
#define NTOK 8224
#define BH_  512
#define FRAG_PER_BH 17408   // TP*HD elements per (b,h) in frag-major arrays

typedef __bf16 bf16;
typedef __bf16 bf16x4 __attribute__((ext_vector_type(4)));
typedef __bf16 bf16x8 __attribute__((ext_vector_type(8)));
typedef short  s16x4  __attribute__((ext_vector_type(4)));
typedef short  s16x8  __attribute__((ext_vector_type(8)));
typedef float  floatx4 __attribute__((ext_vector_type(4)));

static constexpr size_t SZ_XB   = (size_t)NTOK * D_ * 2;
static constexpr size_t SZ_WQKV = (size_t)3 * D_ * D_ * 2;
static constexpr size_t SZ_W    = (size_t)D_ * D_ * 2;
static constexpr size_t SZ_QK   = (size_t)BH_ * FRAG_PER_BH * 2;

static constexpr size_t OFF_XB   = 0;
static constexpr size_t OFF_WQKV = OFF_XB + SZ_XB;
static constexpr size_t OFF_WO   = OFF_WQKV + SZ_WQKV;
static constexpr size_t OFF_Q    = OFF_WO + SZ_W;
static constexpr size_t OFF_K    = OFF_Q + SZ_QK;
static constexpr size_t OFF_V    = OFF_K + SZ_QK;
static constexpr size_t OFF_CTX  = OFF_V + SZ_QK;

#define GLD16(gp, lp)                                                        \
  __builtin_amdgcn_global_load_lds(                                          \
      (const __attribute__((address_space(1))) void*)(gp),                   \
      (__attribute__((address_space(3))) void*)(lp), 16, 0, 0)

// ---------------- fp32 -> bf16 casts ----------------
__global__ void cast_bf16_kernel(const float* __restrict__ src,
                                 bf16* __restrict__ dst, int n4) {
  int i = blockIdx.x * blockDim.x + threadIdx.x;
  int stride = gridDim.x * blockDim.x;
  for (int idx = i; idx < n4; idx += stride) {
    float4 v = reinterpret_cast<const float4*>(src)[idx];
    bf16x4 o;
    o[0] = (bf16)v.x; o[1] = (bf16)v.y; o[2] = (bf16)v.z; o[3] = (bf16)v.w;
    reinterpret_cast<bf16x4*>(dst)[idx] = o;
  }
}

__global__ void cast4_kernel(const float* __restrict__ s0, const float* __restrict__ s1,
                             const float* __restrict__ s2, const float* __restrict__ s3,
                             bf16* __restrict__ d0, bf16* __restrict__ d1,
                             bf16* __restrict__ d2, bf16* __restrict__ d3, int n4) {
  const float* s = (blockIdx.y == 0) ? s0 : (blockIdx.y == 1) ? s1
                   : (blockIdx.y == 2) ? s2 : s3;
  bf16* d = (blockIdx.y == 0) ? d0 : (blockIdx.y == 1) ? d1
            : (blockIdx.y == 2) ? d2 : d3;
  int i = blockIdx.x * blockDim.x + threadIdx.x;
  int stride = gridDim.x * blockDim.x;
  for (int idx = i; idx < n4; idx += stride) {
    float4 v = reinterpret_cast<const float4*>(s)[idx];
    bf16x4 o;
    o[0] = (bf16)v.x; o[1] = (bf16)v.y; o[2] = (bf16)v.z; o[3] = (bf16)v.w;
    reinterpret_cast<bf16x4*>(d)[idx] = o;
  }
}

// Frag-major layouts (element offsets within one bh's 17408 elems):
// Q/K (A/B-op of 16x16x32): [kt(17)][dc(8)][ki(16)][8]  (t=kt*16+ki, d=dc*8+e)
// V   (A-op of 16x16x16, dt-paired): [kt(17)][p(2)][q2(4)][d16(16)][dp(2)][ki(4)]
//     t = kt*16 + q2*4 + ki, d = p*32 + dp*16 + d16.

// ================= fused QKV GEMM: 256x256 tile, 8-phase pipeline =========
// 512 threads = 8 waves (2M x 4N). BK=64, K=1024 -> 16 K-tiles.
// LDS: A[2buf][2half][128x64] at 0, B same at 32768 elems (128KB total).
// XOR swizzle: 16B slot s of row r holds global segment s^(r&7).
// Per K-tile phases (quadrant order 00,01,11,10):
//   ph1: read A(h0)+B(h0), stage (t+1).Ah1 | ph2: read B(h1), stage (t+1).Bh0
//   ph3: read A(h1),       stage (t+2).Ah0 | ph4: no reads,   stage (t+2).Bh1
// Each staged slot's last LDS read was >=1 barrier earlier (derived liveness);
// single s_waitcnt vmcnt(4) per K-tile covers all readiness requirements.

#define PH_MFMA(ACC, AF, BF)                                                 \
  do {                                                                       \
    __builtin_amdgcn_s_setprio(1);                                           \
    _Pragma("unroll") for (int mi_ = 0; mi_ < 4; mi_++)                      \
      _Pragma("unroll") for (int nj_ = 0; nj_ < 2; nj_++)                    \
        _Pragma("unroll") for (int ks_ = 0; ks_ < 2; ks_++)                  \
          ACC[mi_][nj_] = __builtin_amdgcn_mfma_f32_16x16x32_bf16(           \
              AF[mi_][ks_], BF[nj_][ks_], ACC[mi_][nj_], 0, 0, 0);           \
    __builtin_amdgcn_s_setprio(0);                                           \
  } while (0)

#define READ_A(BASE)                                                         \
  do {                                                                       \
    _Pragma("unroll") for (int mi_ = 0; mi_ < 4; mi_++)                      \
      _Pragma("unroll") for (int ks_ = 0; ks_ < 2; ks_++)                    \
        af[mi_][ks_] = *reinterpret_cast<const bf16x8*>(                     \
            smem + (BASE) + aoffs[mi_][ks_]);                                \
  } while (0)

#define READ_B(DST, BASE)                                                    \
  do {                                                                       \
    _Pragma("unroll") for (int nj_ = 0; nj_ < 2; nj_++)                      \
      _Pragma("unroll") for (int ks_ = 0; ks_ < 2; ks_++)                    \
        DST[nj_][ks_] = *reinterpret_cast<const bf16x8*>(                    \
            smem + (BASE) + boffs[nj_][ks_]);                                \
  } while (0)

#define LGKM0                                                                \
  do {                                                                       \
    asm volatile("s_waitcnt lgkmcnt(0)" ::: "memory");                       \
    __builtin_amdgcn_sched_barrier(0);                                       \
  } while (0)

#define TILE4(TT, BB, BBN)                                                   \
  do {                                                                       \
    const int kt1_ = ((TT) + 1 < 16) ? (TT) + 1 : 15;                        \
    const int kt2_ = ((TT) + 2 < 16) ? (TT) + 2 : 15;                        \
    READ_A((BB) * 16384);                                                    \
    READ_B(bf0, 32768 + (BB) * 16384);                                       \
    stageA(BBN, 1, kt1_);                                                    \
    __builtin_amdgcn_s_barrier();                                            \
    LGKM0;                                                                   \
    PH_MFMA(acc00, af, bf0);                                                 \
    __builtin_amdgcn_s_barrier();                                            \
    READ_B(bf1, 32768 + (BB) * 16384 + 8192);                                \
    stageB(BBN, 0, kt1_);                                                    \
    __builtin_amdgcn_s_barrier();                                            \
    LGKM0;                                                                   \
    PH_MFMA(acc01, af, bf1);                                                 \
    __builtin_amdgcn_s_barrier();                                            \
    READ_A((BB) * 16384 + 8192);                                             \
    stageA(BB, 0, kt2_);                                                     \
    __builtin_amdgcn_s_barrier();                                            \
    LGKM0;                                                                   \
    PH_MFMA(acc11, af, bf1);                                                 \
    __builtin_amdgcn_s_barrier();                                            \
    stageB(BB, 1, kt2_);                                                     \
    __builtin_amdgcn_s_barrier();                                            \
    __builtin_amdgcn_sched_barrier(0);                                       \
    PH_MFMA(acc10, af, bf0);                                                 \
    asm volatile("s_waitcnt vmcnt(4)" ::: "memory");                         \
    __builtin_amdgcn_s_barrier();                                            \
  } while (0)

#define EPI_WRITE(ACC_MH0, ACC_MH1, NH)                                      \
  do {                                                                       \
    float bv_[2];                                                            \
    bv_[0] = bias[znb + (NH) * 128 + wc2 * 32 + n15];                        \
    bv_[1] = bias[znb + (NH) * 128 + wc2 * 32 + 16 + n15];                   \
    _Pragma("unroll") for (int mi_ = 0; mi_ < 4; mi_++)                      \
      _Pragma("unroll") for (int nj_ = 0; nj_ < 2; nj_++)                    \
        _Pragma("unroll") for (int r_ = 0; r_ < 4; r_++) {                   \
          int rowL_ = wr2 * 64 + mi_ * 16 + quad * 4 + r_;                   \
          int colL_ = wc2 * 32 + nj_ * 16 + n15;                             \
          smem[rowL_ * 136 + colL_] =                                        \
              (bf16)((ACC_MH0[mi_][nj_][r_] + bv_[nj_]) * scale);            \
          smem[(128 + rowL_) * 136 + colL_] =                                \
              (bf16)((ACC_MH1[mi_][nj_][r_] + bv_[nj_]) * scale);            \
        }                                                                    \
  } while (0)

__global__ __launch_bounds__(512, 2) void qkv_gemm(
    const bf16* __restrict__ xb, const bf16* __restrict__ wqkv,
    const float* __restrict__ bq, const float* __restrict__ bk,
    const float* __restrict__ bv,
    bf16* __restrict__ Qf, bf16* __restrict__ Kf, bf16* __restrict__ Vf) {
  __shared__ bf16 smem[65536];   // 128KB: A dbuf [0,32768), B dbuf [32768,65536)

  const int linear = blockIdx.x;
  const int mt = linear / 12, nt = linear % 12;
  const int m0 = mt * 256, n0 = nt * 256;
  const int tid = threadIdx.x;
  const int lane = tid & 63, w = tid >> 6;
  const int n15 = lane & 15, quad = lane >> 4;
  const int wr2 = w >> 2, wc2 = w & 3;
  const int srow = lane >> 3, sseg = lane & 7;

  // stage one 128x64 half-tile (2 x GLD16 per thread, 16KB total).
  // LDS dest linear; source segment pre-swizzled: slot s of row r gets
  // global segment s^(r&7)  (r&7 == srow here).
  auto stageA = [&](int buf, int half, int kt) {
#pragma unroll
    for (int c = 0; c < 2; c++) {
      int r = (w * 2 + c) * 8 + srow;
      int gm = m0 + half * 128 + r; if (gm > NTOK - 1) gm = NTOK - 1;
      int sg = (sseg ^ srow) * 8;
      GLD16(xb + (size_t)gm * D_ + kt * 64 + sg,
            smem + buf * 16384 + half * 8192 + (w * 2 + c) * 512);
    }
  };
  auto stageB = [&](int buf, int half, int kt) {
#pragma unroll
    for (int c = 0; c < 2; c++) {
      int r = (w * 2 + c) * 8 + srow;
      int gn = n0 + half * 128 + r;
      int sg = (sseg ^ srow) * 8;
      GLD16(wqkv + (size_t)gn * D_ + kt * 64 + sg,
            smem + 32768 + buf * 16384 + half * 8192 + (w * 2 + c) * 512);
    }
  };

  // fragment read offsets within a half (elements), swizzled:
  // row rh, k-seg (ks*4+quad) -> slot (ks*4+quad)^(rh&7); rh&7 == n15&7.
  int aoffs[4][2], boffs[2][2];
#pragma unroll
  for (int mi = 0; mi < 4; mi++)
#pragma unroll
    for (int ks = 0; ks < 2; ks++) {
      int rh = wr2 * 64 + mi * 16 + n15;
      aoffs[mi][ks] = rh * 64 + ((ks * 4 + quad) ^ (n15 & 7)) * 8;
    }
#pragma unroll
  for (int nj = 0; nj < 2; nj++)
#pragma unroll
    for (int ks = 0; ks < 2; ks++) {
      int rh = wc2 * 32 + nj * 16 + n15;
      boffs[nj][ks] = rh * 64 + ((ks * 4 + quad) ^ (n15 & 7)) * 8;
    }

  floatx4 acc00[4][2] = {}, acc01[4][2] = {}, acc10[4][2] = {}, acc11[4][2] = {};
  bf16x8 af[4][2], bf0[2][2], bf1[2][2];

  // prologue: tile0 fully + tile1.{Ah0,Bh1} (the two halves the loop
  // stages two tiles ahead). 12 loads; vmcnt(4) -> tile0 landed.
  stageA(0, 0, 0); stageB(0, 0, 0); stageA(0, 1, 0); stageB(0, 1, 0);
  stageA(1, 0, 1); stageB(1, 1, 1);
  asm volatile("s_waitcnt vmcnt(4)" ::: "memory");
  __builtin_amdgcn_s_barrier();

  for (int t = 0; t < 16; t += 2) {
    TILE4(t, 0, 1);
    TILE4(t + 1, 1, 0);
  }

  // drain the (harmless, clamped) tail stages before reusing LDS.
  asm volatile("s_waitcnt vmcnt(0)" ::: "memory");
  __builtin_amdgcn_s_barrier();

  // ---- epilogue: two 256x128 half-passes, frag-major stores ----
  const int z = nt >> 2;
  bf16* zdst = (z == 0) ? Qf : (z == 1) ? Kf : Vf;
  const float scale = (z == 0) ? 0.125f : 1.0f;
  const float* bias = (z == 0) ? bq : (z == 1) ? bk : bv;
  const int znb = (nt & 3) * 256;

  const int mEnd = (m0 + 256 < NTOK) ? m0 + 256 : NTOK;
  const int span = mEnd - m0;
  const int bA = m0 / T_;
  const int tA = m0 - bA * T_;
  const int tEndA = (tA + span < T_) ? tA + span : T_;
  const int tgA0 = tA >> 4;
  const int nA = ((tEndA - 1) >> 4) - tgA0 + 1;
  int nU = nA, tEndB = 0;
  if (tA + span > T_ && bA + 1 < B_) {
    tEndB = tA + span - T_;
    nU += ((tEndB - 1) >> 4) + 1;
  }

  auto epi_store = [&](int nh_) {
    const int h0 = (nt & 3) * 4 + nh_ * 2;
    for (int u = w; u < nU * 2; u += 8) {
      int g = u >> 1, hh = u & 1;
      int bb, tg, tlo, thi;
      if (g < nA) {
        bb = bA; tg = tgA0 + g;
        tlo = (tA > tg * 16) ? tA : tg * 16;
        int te = tg * 16 + 16; thi = (te < tEndA) ? te : tEndA;
      } else {
        bb = bA + 1; tg = g - nA; tlo = tg * 16;
        int te = tg * 16 + 16; thi = (te < tEndB) ? te : tEndB;
      }
      bf16* gb = zdst + (size_t)(bb * H_ + h0 + hh) * FRAG_PER_BH + tg * 1024;
      const int hc = hh * 64;
      if (z != 2) {
        int ki = lane & 15, dc = lane >> 4;
        int tt = tg * 16 + ki;
        if (tt >= tlo && tt < thi) {
          int rowL = bb * T_ + tt - m0;
          bf16x8 v0 = *reinterpret_cast<const bf16x8*>(smem + rowL * 136 + hc + dc * 8);
          bf16x8 v1 = *reinterpret_cast<const bf16x8*>(smem + rowL * 136 + hc + 32 + dc * 8);
          *reinterpret_cast<bf16x8*>(gb + dc * 128 + ki * 8) = v0;
          *reinterpret_cast<bf16x8*>(gb + 512 + dc * 128 + ki * 8) = v1;
        }
      } else {
        int q2 = (lane >> 4) & 3, d16 = lane & 15;
        int tb = tg * 16 + q2 * 4;
        bool full = (tb >= tlo) && (tb + 3 < thi);
#pragma unroll
        for (int p = 0; p < 2; p++) {
          bf16x8 vv;
#pragma unroll
          for (int dp = 0; dp < 2; dp++)
#pragma unroll
            for (int ki = 0; ki < 4; ki++) {
              int tt = tb + ki;
              int rr = (bb * T_ + tt - m0) & 255;   // safe for masked elems
              vv[dp * 4 + ki] = smem[rr * 136 + hc + p * 32 + dp * 16 + d16];
            }
          bf16* cp = gb + (p * 4 + q2) * 128 + d16 * 8;
          if (full) {
            *reinterpret_cast<bf16x8*>(cp) = vv;
          } else {
#pragma unroll
            for (int dp = 0; dp < 2; dp++)
#pragma unroll
              for (int ki = 0; ki < 4; ki++) {
                int tt = tb + ki;
                if (tt >= tlo && tt < thi) cp[dp * 4 + ki] = vv[dp * 4 + ki];
              }
          }
        }
      }
    }
  };

  EPI_WRITE(acc00, acc10, 0);
  __syncthreads();
  epi_store(0);
  __syncthreads();
  EPI_WRITE(acc01, acc11, 1);
  __syncthreads();
  epi_store(1);
}

// ---------------- fused attention (LDS-staged K/V) ----------------
// grid = 512 (one block per bh), 4 waves; wave w handles q-tiles w, w+4, ...
__global__ __launch_bounds__(256) void attn_kernel(
    const bf16* __restrict__ Qf, const bf16* __restrict__ Kf,
    const bf16* __restrict__ Vf, bf16* __restrict__ ctx) {
  __shared__ bf16 smem[34816];   // K (17408) then V (17408)

  const int bh = blockIdx.x;
  const int tid = threadIdx.x;
  const int lane = tid & 63, w = tid >> 6;
  const int n15 = lane & 15, quad = lane >> 4;
  const int b = bh >> 4, h = bh & 15;

  const bf16* Qb = Qf + (size_t)bh * FRAG_PER_BH;
  const bf16* Kb = Kf + (size_t)bh * FRAG_PER_BH;
  const bf16* Vb = Vf + (size_t)bh * FRAG_PER_BH;

  // stage K and V: 68 chunks of 1KB, 17 per wave
#pragma unroll
  for (int j = 0; j < 17; j++) {
    int c = w * 17 + j;
    const bf16* src = (c < 34) ? (Kb + c * 512) : (Vb + (c - 34) * 512);
    GLD16(src + lane * 8, smem + c * 512);
  }
  __syncthreads();
  const bf16* Ksh = smem;
  const bf16* Vsh = smem + 17408;

  const int fo = quad * 128 + n15 * 8;

  for (int qt = w; qt < 17; qt += 4) {
    bf16x8 qb0 = *reinterpret_cast<const bf16x8*>(Qb + qt * 1024 + fo);
    bf16x8 qb1 = *reinterpret_cast<const bf16x8*>(Qb + qt * 1024 + 512 + fo);

    floatx4 s[17];
#pragma unroll
    for (int kt = 0; kt < 17; kt++) {
      bf16x8 ka0 = *reinterpret_cast<const bf16x8*>(Ksh + kt * 1024 + fo);
      bf16x8 ka1 = *reinterpret_cast<const bf16x8*>(Ksh + kt * 1024 + 512 + fo);
      floatx4 c = {};
      c = __builtin_amdgcn_mfma_f32_16x16x32_bf16(ka0, qb0, c, 0, 0, 0);
      c = __builtin_amdgcn_mfma_f32_16x16x32_bf16(ka1, qb1, c, 0, 0, 0);
      s[kt] = c;
    }
    // keys 257..271 invalid: tile 16 holds keys 256+quad*4+r; only 256 valid
    s[16][1] = -1e30f; s[16][2] = -1e30f; s[16][3] = -1e30f;
    if (quad != 0) s[16][0] = -1e30f;

    float m0 = -1e30f;
#pragma unroll
    for (int kt = 0; kt < 17; kt++)
#pragma unroll
      for (int r = 0; r < 4; r++) m0 = fmaxf(m0, s[kt][r]);
    m0 = fmaxf(m0, __shfl_xor(m0, 16));
    m0 = fmaxf(m0, __shfl_xor(m0, 32));

    float sum = 0.f;
    s16x4 pb[17];
#pragma unroll
    for (int kt = 0; kt < 17; kt++) {
      bf16x4 ph;
#pragma unroll
      for (int r = 0; r < 4; r++) {
        float p = __expf(s[kt][r] - m0);
        sum += p;
        ph[r] = (bf16)p;
      }
      pb[kt] = __builtin_bit_cast(s16x4, ph);
    }
    sum += __shfl_xor(sum, 16);
    sum += __shfl_xor(sum, 32);

    floatx4 o[4] = {};
#pragma unroll
    for (int kt = 0; kt < 17; kt++) {
#pragma unroll
      for (int p = 0; p < 2; p++) {
        bf16x8 vv = *reinterpret_cast<const bf16x8*>(
            Vsh + ((kt * 2 + p) * 4 + quad) * 128 + n15 * 8);
        s16x8 v16 = __builtin_bit_cast(s16x8, vv);
        s16x4 vlo = __builtin_shufflevector(v16, v16, 0, 1, 2, 3);
        s16x4 vhi = __builtin_shufflevector(v16, v16, 4, 5, 6, 7);
        o[p * 2]     = __builtin_amdgcn_mfma_f32_16x16x16bf16_1k(vlo, pb[kt], o[p * 2], 0, 0, 0);
        o[p * 2 + 1] = __builtin_amdgcn_mfma_f32_16x16x16bf16_1k(vhi, pb[kt], o[p * 2 + 1], 0, 0, 0);
      }
    }

    int q = qt * 16 + n15;
    if (q < T_) {
      float inv = 1.0f / sum;
      size_t ob = ((size_t)(b * T_ + q)) * D_ + h * 64 + quad * 4;
#pragma unroll
      for (int dt = 0; dt < 4; dt++) {
        bf16x4 ov;
#pragma unroll
        for (int r = 0; r < 4; r++) ov[r] = (bf16)(o[dt][r] * inv);
        *reinterpret_cast<bf16x4*>(ctx + ob + dt * 16) = ov;
      }
    }
  }
}

// ---------------- output projection GEMM (fp32 out) ----------------
__global__ __launch_bounds__(256) void o_gemm(
    const bf16* __restrict__ ctx, const bf16* __restrict__ wo,
    const float* __restrict__ bo, float* __restrict__ out) {
  __shared__ bf16 Ash[128 * 32];
  __shared__ bf16 Bsh[128 * 32];

  const int linear = blockIdx.x;
  const int nbase = (linear & 7) * 128;
  const int mbase = (linear >> 3) * 128;
  const int tid = threadIdx.x;
  const int lane = tid & 63;
  const int w = tid >> 6;
  const int wr = w >> 1, wc = w & 1;
  const int n15 = lane & 15, quad = lane >> 4;

  const int lrow = lane >> 2;
  const int lseg = (lane & 3) * 8;

  floatx4 acc[4][4] = {};

  for (int k0 = 0; k0 < D_; k0 += 32) {
#pragma unroll
    for (int c = 0; c < 2; c++) {
      int r0 = w * 32 + c * 16;
      int row = r0 + lrow;
      int gm = mbase + row; if (gm > NTOK - 1) gm = NTOK - 1;
      GLD16(ctx + (size_t)gm * D_ + k0 + lseg, Ash + r0 * 32);
      GLD16(wo + (size_t)(nbase + row) * D_ + k0 + lseg, Bsh + r0 * 32);
    }
    __syncthreads();
    bf16x8 af[4], bfr[4];
#pragma unroll
    for (int i = 0; i < 4; i++) {
      af[i]  = *reinterpret_cast<const bf16x8*>(Ash + (wr * 64 + i * 16 + n15) * 32 + quad * 8);
      bfr[i] = *reinterpret_cast<const bf16x8*>(Bsh + (wc * 64 + i * 16 + n15) * 32 + quad * 8);
    }
#pragma unroll
    for (int i = 0; i < 4; i++)
#pragma unroll
      for (int j = 0; j < 4; j++)
        acc[i][j] = __builtin_amdgcn_mfma_f32_16x16x32_bf16(af[i], bfr[j], acc[i][j], 0, 0, 0);
    __syncthreads();
  }

#pragma unroll
  for (int i = 0; i < 4; i++) {
    int rowb = mbase + wr * 64 + i * 16 + quad * 4;
#pragma unroll
    for (int j = 0; j < 4; j++) {
      int col = nbase + wc * 64 + j * 16 + n15;
      float bval = bo[col];
#pragma unroll
      for (int r = 0; r < 4; r++) {
        int m = rowb + r;
        if (m < NTOK) out[(size_t)m * D_ + col] = acc[i][j][r] + bval;
      }
    }
  }
}

extern "C" void kernel_launch(void* const* d_in, const int* in_sizes, int n_in,
                              void* d_out, int out_size, void* d_ws, size_t ws_size,
                              hipStream_t stream) {
  const float* hs = (const float*)d_in[0];
  const float* Wq = (const float*)d_in[1];
  const float* bq = (const float*)d_in[2];
  const float* Wk = (const float*)d_in[3];
  const float* bk = (const float*)d_in[4];
  const float* Wv = (const float*)d_in[5];
  const float* bv = (const float*)d_in[6];
  const float* Wo = (const float*)d_in[7];
  const float* bo = (const float*)d_in[8];

  char* ws = (char*)d_ws;
  bf16* xb   = (bf16*)(ws + OFF_XB);
  bf16* wqkv = (bf16*)(ws + OFF_WQKV);
  bf16* wob  = (bf16*)(ws + OFF_WO);
  bf16* Qfw  = (bf16*)(ws + OFF_Q);
  bf16* Kfw  = (bf16*)(ws + OFF_K);
  bf16* Vfw  = (bf16*)(ws + OFF_V);
  bf16* ctx  = (bf16*)(ws + OFF_CTX);

  cast_bf16_kernel<<<2048, 256, 0, stream>>>(hs, xb, NTOK * D_ / 4);
  cast4_kernel<<<dim3(256, 4), 256, 0, stream>>>(
      Wq, Wk, Wv, Wo,
      wqkv, wqkv + (size_t)D_ * D_, wqkv + (size_t)2 * D_ * D_, wob,
      D_ * D_ / 4);

  qkv_gemm<<<396, 512, 0, stream>>>(xb, wqkv, bq, bk, bv, Qfw, Kfw, Vfw);
  attn_kernel<<<BH_, 256, 0, stream>>>(Qfw, Kfw, Vfw, ctx);
  o_gemm<<<520, 256, 0, stream>>>(ctx, wob, bo, (float*)d_out);
}